// Round 6
// baseline (1152.608 us; speedup 1.0000x reference)
//
#include <hip/hip_runtime.h>

#define HH 512
#define WW 512
#define HWSZ (HH * WW)

// LDS layout (float offsets). All float4-group bases are 16B-aligned.
#define O_W1 0      // 7x16
#define O_B1 112    // 16
#define O_W2 128    // 16x16
#define O_B2 384    // 16
#define O_W3 400    // 16x16
#define O_B3 656    // 16
#define O_W4 672    // 16x16
#define O_B4 928    // 16
#define O_W5 944    // 16x4 (padded from 16x3)
#define O_B5 1008   // 4 (padded from 3)
#define SW_TOT 1012

// Scheduler fence (mask 0 = nothing crosses). Bounds each layer's weight
// live-range. R4: without it, full unroll hoisted all ~1012 weight floats ->
// VGPR=256 -> 4.3 GB scratch. R5: with it, VGPR=40, no spill. Keep it.
#define LAYER_FENCE() __builtin_amdgcn_sched_barrier(0)

// ---------------------------------------------------------------------------
// Pre-pass: transpose featuremap (C,H,W) -> (H,W,C): one bilinear corner = one
// aligned float4 load.
// ---------------------------------------------------------------------------
__global__ void fm_transpose(const float* __restrict__ fm, float* __restrict__ fmT) {
    int i = blockIdx.x * blockDim.x + threadIdx.x;
    if (i < HWSZ) {
        float4 v;
        v.x = fm[i];
        v.y = fm[HWSZ + i];
        v.z = fm[2 * HWSZ + i];
        v.w = fm[3 * HWSZ + i];
        reinterpret_cast<float4*>(fmT)[i] = v;
    }
}

// ---------------------------------------------------------------------------
// Fused grid_sample + MLP, 4 points/thread.
// R5 post-mortem: 1 pt/thread was LDS-pipe-bound — 253 uniform ds_read_b128
// per wave at ~6 cyc on the per-CU LDS port (4 SIMDs sharing) = 154 us,
// matching the measured 161 us; the VALU floor is only ~52 us. With 4
// pts/thread one ds_read_b128 (4 weights) feeds 16 FMAs (4 cols x 4 pts):
// LDS time /4 -> ~39 us < VALU -> VALU-bound.
// Weights stay in LDS (uniform broadcast, conflict-free, can't scalarize to
// SGPRs — R1/R3 spill pathologies) with sched_barrier(0) between layers.
// ---------------------------------------------------------------------------
template <bool TR>
__global__ __launch_bounds__(256) void mlp_fused(
    const float* __restrict__ x, const float* __restrict__ fm,
    const float* __restrict__ W1, const float* __restrict__ b1,
    const float* __restrict__ W2, const float* __restrict__ b2,
    const float* __restrict__ W3, const float* __restrict__ b3,
    const float* __restrict__ W4, const float* __restrict__ b4,
    const float* __restrict__ W5, const float* __restrict__ b5,
    float* __restrict__ out, int n)
{
    __shared__ __align__(16) float sW[SW_TOT];
    const int tid = threadIdx.x;

    // ---- stage weights into LDS (one pass; 256 threads) ----
    if (tid < 112) sW[O_W1 + tid] = W1[tid];
    if (tid < 16) {
        sW[O_B1 + tid] = b1[tid];
        sW[O_B2 + tid] = b2[tid];
        sW[O_B3 + tid] = b3[tid];
        sW[O_B4 + tid] = b4[tid];
    }
    {   // W2/W3/W4: exactly one element per thread
        sW[O_W2 + tid] = W2[tid];
        sW[O_W3 + tid] = W3[tid];
        sW[O_W4 + tid] = W4[tid];
    }
    if (tid < 64) {  // W5 padded 16x3 -> 16x4
        int r = tid >> 2, c = tid & 3;
        sW[O_W5 + tid] = (c < 3) ? W5[r * 3 + c] : 0.f;
    }
    if (tid < 4) sW[O_B5 + tid] = (tid < 3) ? b5[tid] : 0.f;
    __syncthreads();

    const int t  = blockIdx.x * blockDim.x + tid;
    const int i0 = 4 * t;
    if (i0 >= n) return;  // after the barrier: safe
    const bool full = (i0 + 3 < n);

    // ---- load 4 points' coords (48 B = 3 x float4, 16B-aligned) ----
    float px[4][3];
    if (full) {
        const float4* x4 = reinterpret_cast<const float4*>(x) + 3 * t;
        float4 a = x4[0], b = x4[1], c = x4[2];
        px[0][0] = a.x; px[0][1] = a.y; px[0][2] = a.z;
        px[1][0] = a.w; px[1][1] = b.x; px[1][2] = b.y;
        px[2][0] = b.z; px[2][1] = b.w; px[2][2] = c.x;
        px[3][0] = c.y; px[3][1] = c.z; px[3][2] = c.w;
    } else {
#pragma unroll
        for (int p = 0; p < 4; ++p) {
            int ip = (i0 + p < n) ? (i0 + p) : i0;
            px[p][0] = x[3 * ip]; px[p][1] = x[3 * ip + 1]; px[p][2] = x[3 * ip + 2];
        }
    }

    // ---- bilinear sample x4, border clamp (identical arithmetic to ref) ----
    float feat[4][4];
#pragma unroll
    for (int p = 0; p < 4; ++p) {
        float gx = px[p][0] * 2.f - 1.f;
        float gy = px[p][1] * 2.f - 1.f;
        float fx = ((gx + 1.f) * (float)WW - 1.f) * 0.5f;
        float fy = ((gy + 1.f) * (float)HH - 1.f) * 0.5f;
        fx = fminf(fmaxf(fx, 0.f), (float)(WW - 1));
        fy = fminf(fmaxf(fy, 0.f), (float)(HH - 1));
        float x0f = floorf(fx), y0f = floorf(fy);
        float wx = fx - x0f, wy = fy - y0f;
        int ix0 = (int)x0f, iy0 = (int)y0f;
        int ix1 = min(ix0 + 1, WW - 1);
        int iy1 = min(iy0 + 1, HH - 1);
        float w00 = (1.f - wy) * (1.f - wx);
        float w01 = (1.f - wy) * wx;
        float w10 = wy * (1.f - wx);
        float w11 = wy * wx;
        if (TR) {
            const float4* fmT = reinterpret_cast<const float4*>(fm);
            float4 v00 = fmT[iy0 * WW + ix0];
            float4 v01 = fmT[iy0 * WW + ix1];
            float4 v10 = fmT[iy1 * WW + ix0];
            float4 v11 = fmT[iy1 * WW + ix1];
            feat[p][0] = v00.x * w00 + v01.x * w01 + v10.x * w10 + v11.x * w11;
            feat[p][1] = v00.y * w00 + v01.y * w01 + v10.y * w10 + v11.y * w11;
            feat[p][2] = v00.z * w00 + v01.z * w01 + v10.z * w10 + v11.z * w11;
            feat[p][3] = v00.w * w00 + v01.w * w01 + v10.w * w10 + v11.w * w11;
        } else {
#pragma unroll
            for (int ch = 0; ch < 4; ++ch) {
                const float* f = fm + ch * HWSZ;
                feat[p][ch] = f[iy0 * WW + ix0] * w00 + f[iy0 * WW + ix1] * w01 +
                              f[iy1 * WW + ix0] * w10 + f[iy1 * WW + ix1] * w11;
            }
        }
    }

    // ---- MLP from LDS weights; one ds_read_b128 feeds 16 FMAs ----
    const float4* sW1v = reinterpret_cast<const float4*>(sW + O_W1);
    const float4* sB1v = reinterpret_cast<const float4*>(sW + O_B1);
    const float4* sW2v = reinterpret_cast<const float4*>(sW + O_W2);
    const float4* sB2v = reinterpret_cast<const float4*>(sW + O_B2);
    const float4* sW3v = reinterpret_cast<const float4*>(sW + O_W3);
    const float4* sB3v = reinterpret_cast<const float4*>(sW + O_B3);
    const float4* sW4v = reinterpret_cast<const float4*>(sW + O_W4);
    const float4* sB4v = reinterpret_cast<const float4*>(sW + O_B4);
    const float4* sW5v = reinterpret_cast<const float4*>(sW + O_W5);

    float in[4][7];
#pragma unroll
    for (int p = 0; p < 4; ++p) {
        in[p][0] = px[p][0]; in[p][1] = px[p][1]; in[p][2] = px[p][2];
        in[p][3] = feat[p][0]; in[p][4] = feat[p][1];
        in[p][5] = feat[p][2]; in[p][6] = feat[p][3];
    }
    float h[4][16], g[4][16];

    LAYER_FENCE();
    // layer 1: 7 -> 16, relu
#pragma unroll
    for (int jg = 0; jg < 4; ++jg) {
        float4 bb = sB1v[jg];
        float4 acc[4];
#pragma unroll
        for (int p = 0; p < 4; ++p) acc[p] = bb;
#pragma unroll
        for (int k = 0; k < 7; ++k) {
            float4 w = sW1v[k * 4 + jg];
#pragma unroll
            for (int p = 0; p < 4; ++p) {
                float u = in[p][k];
                acc[p].x = fmaf(u, w.x, acc[p].x);
                acc[p].y = fmaf(u, w.y, acc[p].y);
                acc[p].z = fmaf(u, w.z, acc[p].z);
                acc[p].w = fmaf(u, w.w, acc[p].w);
            }
        }
#pragma unroll
        for (int p = 0; p < 4; ++p) {
            h[p][jg * 4 + 0] = fmaxf(acc[p].x, 0.f);
            h[p][jg * 4 + 1] = fmaxf(acc[p].y, 0.f);
            h[p][jg * 4 + 2] = fmaxf(acc[p].z, 0.f);
            h[p][jg * 4 + 3] = fmaxf(acc[p].w, 0.f);
        }
    }
    LAYER_FENCE();

#define LAYER16(WV, BV, src, dst)                                      \
    _Pragma("unroll")                                                  \
    for (int jg = 0; jg < 4; ++jg) {                                   \
        float4 bb = (BV)[jg];                                          \
        float4 acc[4];                                                 \
        _Pragma("unroll")                                              \
        for (int p = 0; p < 4; ++p) acc[p] = bb;                       \
        _Pragma("unroll")                                              \
        for (int k = 0; k < 16; ++k) {                                 \
            float4 w = (WV)[k * 4 + jg];                               \
            _Pragma("unroll")                                          \
            for (int p = 0; p < 4; ++p) {                              \
                float u = (src)[p][k];                                 \
                acc[p].x = fmaf(u, w.x, acc[p].x);                     \
                acc[p].y = fmaf(u, w.y, acc[p].y);                     \
                acc[p].z = fmaf(u, w.z, acc[p].z);                     \
                acc[p].w = fmaf(u, w.w, acc[p].w);                     \
            }                                                          \
        }                                                              \
        _Pragma("unroll")                                              \
        for (int p = 0; p < 4; ++p) {                                  \
            (dst)[p][jg * 4 + 0] = fmaxf(acc[p].x, 0.f);               \
            (dst)[p][jg * 4 + 1] = fmaxf(acc[p].y, 0.f);               \
            (dst)[p][jg * 4 + 2] = fmaxf(acc[p].z, 0.f);               \
            (dst)[p][jg * 4 + 3] = fmaxf(acc[p].w, 0.f);               \
        }                                                              \
    }

    LAYER16(sW2v, sB2v, h, g)
    LAYER_FENCE();
    LAYER16(sW3v, sB3v, g, h)
    LAYER_FENCE();
    LAYER16(sW4v, sB4v, h, g)
    LAYER_FENCE();
#undef LAYER16

    // layer 5: 16 -> 3 (padded to 4), no relu
    float4 bb5 = *reinterpret_cast<const float4*>(sW + O_B5);
    float4 acc[4];
#pragma unroll
    for (int p = 0; p < 4; ++p) acc[p] = bb5;
#pragma unroll
    for (int k = 0; k < 16; ++k) {
        float4 w = sW5v[k];
#pragma unroll
        for (int p = 0; p < 4; ++p) {
            float u = g[p][k];
            acc[p].x = fmaf(u, w.x, acc[p].x);
            acc[p].y = fmaf(u, w.y, acc[p].y);
            acc[p].z = fmaf(u, w.z, acc[p].z);
        }
    }

    // ---- store 4 points (48 B = 3 x float4) ----
    if (full) {
        float4* o4 = reinterpret_cast<float4*>(out) + 3 * t;
        o4[0] = make_float4(acc[0].x, acc[0].y, acc[0].z, acc[1].x);
        o4[1] = make_float4(acc[1].y, acc[1].z, acc[2].x, acc[2].y);
        o4[2] = make_float4(acc[2].z, acc[3].x, acc[3].y, acc[3].z);
    } else {
#pragma unroll
        for (int p = 0; p < 4; ++p) {
            if (i0 + p < n) {
                out[3 * (i0 + p)]     = acc[p].x;
                out[3 * (i0 + p) + 1] = acc[p].y;
                out[3 * (i0 + p) + 2] = acc[p].z;
            }
        }
    }
}

extern "C" void kernel_launch(void* const* d_in, const int* in_sizes, int n_in,
                              void* d_out, int out_size, void* d_ws, size_t ws_size,
                              hipStream_t stream) {
    const float* x  = (const float*)d_in[0];
    const float* fm = (const float*)d_in[1];
    const float* W1 = (const float*)d_in[2];
    const float* b1 = (const float*)d_in[3];
    const float* W2 = (const float*)d_in[4];
    const float* b2 = (const float*)d_in[5];
    const float* W3 = (const float*)d_in[6];
    const float* b3 = (const float*)d_in[7];
    const float* W4 = (const float*)d_in[8];
    const float* b4 = (const float*)d_in[9];
    const float* W5 = (const float*)d_in[10];
    const float* b5 = (const float*)d_in[11];
    float* out = (float*)d_out;

    const int n = in_sizes[0] / 3;  // 4,000,000 points
    const int block = 256;
    const int threads = (n + 3) / 4;
    const int grid = (threads + block - 1) / block;

    const size_t need = (size_t)HWSZ * 4 * sizeof(float);  // 4 MB
    if (ws_size >= need) {
        float* fmT = (float*)d_ws;
        fm_transpose<<<(HWSZ + 255) / 256, 256, 0, stream>>>(fm, fmT);
        mlp_fused<true><<<grid, block, 0, stream>>>(x, fmT, W1, b1, W2, b2, W3, b3,
                                                    W4, b4, W5, b5, out, n);
    } else {
        mlp_fused<false><<<grid, block, 0, stream>>>(x, fm, W1, b1, W2, b2, W3, b3,
                                                     W4, b4, W5, b5, out, n);
    }
}